// Round 13
// baseline (107.613 us; speedup 1.0000x reference)
//
#include <hip/hip_runtime.h>

// Problem constants: m=4, h=16, t=1024, d=128, MAX_REL=128.
constexpr int D_DIM = 128;
constexpr int T_Q   = 1024;
constexpr int NPE   = 257;               // 2*MAX_REL + 1 pe rows
constexpr int WAVES = 4;                 // 256-thread block, NO barriers
constexpr int BLOCK_THREADS  = WAVES * 64;
constexpr int ROWS_PER_WAVE  = 16;       // one 16-row MFMA M-tile per wave
constexpr int ROWS_PER_BLOCK = WAVES * ROWS_PER_WAVE;   // 64; grid 1024 -> 4 blocks/CU

typedef __attribute__((ext_vector_type(8))) short short8;  // bf16x8 MFMA operand
typedef __attribute__((ext_vector_type(4))) float f32x4;   // MFMA accumulator

// readlane: uniform lane index -> SGPR broadcast, no DS/memory.
#define RL(V, SRC) __uint_as_float(__builtin_amdgcn_readlane(__float_as_uint(V), (SRC)))

// ---- Kernel P: pe f32 -> bf16 (RNE) in d_ws. 65.8 KB, L2-resident after. ----
__global__ void pe_prep(const float* __restrict__ pe, ushort* __restrict__ pb)
{
    const int i = blockIdx.x * blockDim.x + threadIdx.x;
    if (i < NPE * D_DIM) {
        const uint u = __float_as_uint(pe[i]);
        pb[i] = (ushort)((u + 0x7FFFu + ((u >> 16) & 1u)) >> 16);
    }
}

// ---- Kernel M: window GEMM + expand. Per wave: D[16 rows][257] = Q_tile.pe^T.
// Precision: pe bf16 RNE; q = hi + lo (truncation split), 2 MFMA passes.
// Layout contract (k-permutation-invariant): A row m = lane&15, B col n =
// lane&15, k-dims {32kk+8g+e} in matching slots. C/D (HW-verified m89):
// col = lane&15, row = (lane>>4)*4 + reg.
//
// NO __syncthreads, no shared staging: pe-bf16 fragments are read straight
// from d_ws (L2-hot; a 64-lane x 16B load touches 16 lines regardless of the
// row stride, so this coalesces exactly like a linear dwordx4 load). Waves
// are fully independent -> free drift: store bursts of some waves overlap
// MFMA/DS of others. All loads complete before the first store, so no
// vmcnt wait can ever force a store-queue drain.
//
// Epilogue (as r11/r12): per row c=row&3, window stored REVERSED with shift c
// into rev[u][p] (pads cover the clip regions); out[s0..s0+3] is ONE aligned
// ds_read_b128; far-clip groups splat r0/r256. rev is per-wave; DS pipe
// in-order per wave makes write->read safe without barriers.
__global__ __launch_bounds__(BLOCK_THREADS, 4)   // <=128 VGPR; need ~110
void rpe_mfma(const float* __restrict__ Q,
              const ushort* __restrict__ pb,
              float* __restrict__ out)
{
    __shared__ float rev[WAVES][4][264];          // 16.9 KB -> 4+ blocks/CU

    const int tid = threadIdx.x;
    const int w   = tid >> 6;
    const int l   = tid & 63;
    const int n15 = l & 15;
    const int g   = l >> 4;

    const int waveRow0 = blockIdx.x * ROWS_PER_BLOCK + w * ROWS_PER_WAVE;

    // ---- A-fragments: lane holds row (waveRow0 + n15), dims 32kk+8g..+7. ----
    const float* qrow = Q + (size_t)(waveRow0 + n15) * D_DIM;
    short8 ahi[4], alo[4];
#pragma unroll
    for (int kk = 0; kk < 4; ++kk) {
        const int base = 32 * kk + 8 * g;
        const float4 a0 = *reinterpret_cast<const float4*>(qrow + base);
        const float4 a1 = *reinterpret_cast<const float4*>(qrow + base + 4);
        const float av[8] = {a0.x, a0.y, a0.z, a0.w, a1.x, a1.y, a1.z, a1.w};
#pragma unroll
        for (int e = 0; e < 8; ++e) {
            const uint u = __float_as_uint(av[e]);
            ahi[kk][e] = (short)(u >> 16);                   // truncation: residual exact
            const float fl = av[e] - __uint_as_float(u & 0xffff0000u);
            alo[kk][e] = (short)(__float_as_uint(fl) >> 16);
        }
    }

    // ---- MFMA main: 16 n-tiles x 4 k-steps x 2 passes = 128 MFMA/wave.
    //      B fragments straight from L2-hot pb; fully unrolled -> the compiler
    //      hoists loads ahead of MFMAs under counted vmcnt. ----
    f32x4 acc[16];
#pragma unroll
    for (int j = 0; j < 16; ++j) acc[j] = (f32x4){0.f, 0.f, 0.f, 0.f};

#pragma unroll
    for (int kk = 0; kk < 4; ++kk) {
        const int kof = 32 * kk + 8 * g;
#pragma unroll
        for (int j = 0; j < 16; ++j) {
            const short8 bh = *reinterpret_cast<const short8*>(pb + (16 * j + n15) * 128 + kof);
            acc[j] = __builtin_amdgcn_mfma_f32_16x16x32_bf16(ahi[kk], bh, acc[j], 0, 0, 0);
            acc[j] = __builtin_amdgcn_mfma_f32_16x16x32_bf16(alo[kk], bh, acc[j], 0, 0, 0);
        }
    }

    // ---- rel[256] per row: lane partial over its 32 dims of row n15,
    //      xor16+xor32 combine g-groups -> lane l holds rel256 of row l&15. ----
    float rel_part = 0.f;
#pragma unroll
    for (int kk = 0; kk < 4; ++kk) {
        const short8 ph = *reinterpret_cast<const short8*>(pb + 256 * 128 + 32 * kk + 8 * g);
#pragma unroll
        for (int e = 0; e < 8; ++e) {
            const float qv = __uint_as_float(((uint)(ushort)ahi[kk][e]) << 16)
                           + __uint_as_float(((uint)(ushort)alo[kk][e]) << 16);
            const float pv = __uint_as_float(((uint)(ushort)ph[e]) << 16);
            rel_part = fmaf(qv, pv, rel_part);
        }
    }
    rel_part += __shfl_xor(rel_part, 16, 64);
    rel_part += __shfl_xor(rel_part, 32, 64);

    // ---- epilogue: rows grouped by c = row&3 (4 rows per group, u slot = g).
    //      Spill reversed+shifted window (full-lane), pads, then 4 rows x
    //      4 k-groups of {splat | one aligned b128 read} + store. ----
#pragma unroll
    for (int c = 0; c < 4; ++c) {
        // main spill: win[16j+n15] of row 4g+c -> rev[w][g][256 + c - 16j - n15]
#pragma unroll
        for (int j = 0; j < 16; ++j)
            rev[w][g][256 + c - 16 * j - n15] = acc[j][c];

        // pads + win[256]: lanes of group g serve sub-buffer u=g.
        {
            const float rel_r = __shfl(rel_part, 4 * g + c, 64);   // rel256 of row 4g+c
            const float r0_r  = __shfl(acc[0][c], 16 * g, 64);     // win[0]  of row 4g+c
            if (n15 <= 3) {
                if (n15 <= c) rev[w][g][n15] = rel_r;              // p in [0, c]
            } else if (n15 <= 10) {
                const int p = 253 + n15;                           // p in [257, 263]
                if (p >= 257 + c) rev[w][g][p] = r0_r;
            }
        }
        // DS in-order per wave + may-alias: reads below observe writes above.

#pragma unroll
        for (int u = 0; u < 4; ++u) {
            const int gRow = waveRow0 + 4 * u + c;
            const int t = gRow & (T_Q - 1);                        // t === c (mod 4)
            const int ofs = 128 - t + c;
            float* orow = out + (size_t)gRow * T_Q;
            const float rr256 = RL(rel_part, 4 * u + c);
            const float rr0   = RL(acc[0][c], 16 * u);

#pragma unroll
            for (int k = 0; k < 4; ++k) {
                const int s0 = 4 * l + 256 * k;
                const int j0 = t + 128 - s0;          // jraw at first component
                float4 v;
                if (j0 <= 0) {                         // all right-clipped -> win[0]
                    v = make_float4(rr0, rr0, rr0, rr0);
                } else if (j0 >= 259) {                // all left-clipped -> win[256]
                    v = make_float4(rr256, rr256, rr256, rr256);
                } else {                               // one aligned b128: p0 = s0+ofs
                    v = *reinterpret_cast<const float4*>(&rev[w][u][s0 + ofs]);
                }
                reinterpret_cast<float4*>(orow)[l + 64 * k] = v;   // fire-and-forget
            }
        }
        // next c's spill writes cannot pass this c's gather reads (DS in-order).
    }
}

extern "C" void kernel_launch(void* const* d_in, const int* in_sizes, int n_in,
                              void* d_out, int out_size, void* d_ws, size_t ws_size,
                              hipStream_t stream)
{
    const float* Q  = (const float*)d_in[0];
    // d_in[1] is K: only its shape matters (t_k = 1024), data unused.
    const float* pe = (const float*)d_in[2];
    float* out = (float*)d_out;
    ushort* pb = (ushort*)d_ws;                        // 65792 B (ws is MBs)

    // P: pe -> bf16 (stream-ordered before M)
    pe_prep<<<(NPE * D_DIM + 255) / 256, 256, 0, stream>>>(pe, pb);

    // M: barrier-free main kernel
    const int total_rows = in_sizes[0] / D_DIM;        // m*h*t = 65536
    const int grid = total_rows / ROWS_PER_BLOCK;      // 1024 -> 4 blocks/CU
    rpe_mfma<<<grid, BLOCK_THREADS, 0, stream>>>(Q, pb, out);
}

// Round 14
// 70.066 us; speedup vs baseline: 1.5359x; 1.5359x over previous
//
#include <hip/hip_runtime.h>

// Problem constants: m=4, h=16, t=1024, d=128, MAX_REL=128.
constexpr int D_DIM = 128;
constexpr int T_Q   = 1024;
constexpr int NPE   = 257;               // 2*MAX_REL + 1 pe rows
constexpr int WAVES = 4;                 // 256-thread block
constexpr int BLOCK_THREADS  = WAVES * 64;
constexpr int ROWS_PER_WAVE  = 16;       // one 16-row MFMA M-tile per wave
constexpr int ROWS_PER_BLOCK = WAVES * ROWS_PER_WAVE;   // 64; grid 1024
// LDS 65.8 KB/block -> 2 RESIDENT blocks/CU, 4 assigned -> 2 sequential shifts:
// a shift-2 block's staging+MFMA overlaps the other shift-1 block's store drain.

typedef __attribute__((ext_vector_type(8))) short short8;  // bf16x8 MFMA operand
typedef __attribute__((ext_vector_type(4))) float f32x4;   // MFMA accumulator

// readlane: uniform lane index -> SGPR broadcast, no DS/memory.
#define RL(V, SRC) __uint_as_float(__builtin_amdgcn_readlane(__float_as_uint(V), (SRC)))

// Window GEMM per wave: D[16 rows][257 pe-rows] = Q_tile . pe^T, K=128.
// Precision: pe -> bf16 RNE; q -> hi + lo (truncation split), 2 MFMA passes.
// Layout contract (k-permutation-invariant): A row m = lane&15, B col n =
// lane&15, k-dims {32kk+8g+e} in matching slots. C/D (HW-verified m89):
// col = lane&15, row = (lane>>4)*4 + reg.
//
// LDS phases (UNION, 65.8 KB):
//   phase 1 (staging .. rel256): phi = bf16 [257][128], rotated +8*(n&15)
//   phase 2 (epilogue, after __syncthreads): rev[4][4][264] f32 (16.9 KB)
//
// Epilogue (as r11/r12): per row c=row&3, window stored REVERSED with shift c
// into rev[u][p] (pads cover clip regions); out[s0..s0+3] = one aligned
// ds_read_b128; far-clip groups splat r0/r256. DS in-order per wave makes
// the write->read sequences safe without extra barriers.
__global__ __launch_bounds__(BLOCK_THREADS, 4)   // <=128 VGPR; need ~110
void rpe_mfma(const float* __restrict__ Q,
              const float* __restrict__ pe,
              float* __restrict__ out)
{
    __shared__ char smem_raw[NPE * 128 * 2];     // 65792 B, overlaid phases
    ushort* phi = reinterpret_cast<ushort*>(smem_raw);
    float (*rev)[4][264] = reinterpret_cast<float(*)[4][264]>(smem_raw);

    const int tid = threadIdx.x;
    const int w   = tid >> 6;
    const int l   = tid & 63;
    const int n15 = l & 15;
    const int g   = l >> 4;

    // ---- stage pe -> phi as bf16 (RNE), rotated; vectorized: one float4
    //      read -> one ds_write_b64 of 4 bf16 (posr0 multiple of 4, no wrap). ----
    for (int q4 = tid; q4 < NPE * 32; q4 += BLOCK_THREADS) {
        const int n  = q4 >> 5;
        const int d0 = (q4 & 31) * 4;
        const float4 f = *reinterpret_cast<const float4*>(pe + n * 128 + d0);
        const float fv[4] = {f.x, f.y, f.z, f.w};
        ushort h[4];
#pragma unroll
        for (int e = 0; e < 4; ++e) {
            const uint u = __float_as_uint(fv[e]);
            h[e] = (ushort)((u + 0x7FFFu + ((u >> 16) & 1u)) >> 16);   // RNE
        }
        const int posr0 = (d0 + 8 * (n & 15)) & 127;
        *reinterpret_cast<uint2*>(&phi[n * 128 + posr0]) = *reinterpret_cast<uint2*>(h);
    }
    __syncthreads();

    const int waveRow0 = blockIdx.x * ROWS_PER_BLOCK + w * ROWS_PER_WAVE;

    // ---- A-fragments: lane holds row (waveRow0 + n15), dims 32kk+8g..+7. ----
    const float* qrow = Q + (size_t)(waveRow0 + n15) * D_DIM;
    short8 ahi[4], alo[4];
#pragma unroll
    for (int kk = 0; kk < 4; ++kk) {
        const int base = 32 * kk + 8 * g;
        const float4 a0 = *reinterpret_cast<const float4*>(qrow + base);
        const float4 a1 = *reinterpret_cast<const float4*>(qrow + base + 4);
        const float av[8] = {a0.x, a0.y, a0.z, a0.w, a1.x, a1.y, a1.z, a1.w};
#pragma unroll
        for (int e = 0; e < 8; ++e) {
            const uint u = __float_as_uint(av[e]);
            ahi[kk][e] = (short)(u >> 16);                   // truncation: residual exact
            const float fl = av[e] - __uint_as_float(u & 0xffff0000u);
            alo[kk][e] = (short)(__float_as_uint(fl) >> 16);
        }
    }

    // ---- MFMA main: 16 n-tiles x 4 k-steps x 2 passes = 128 MFMA/wave. ----
    f32x4 acc[16];
#pragma unroll
    for (int j = 0; j < 16; ++j) acc[j] = (f32x4){0.f, 0.f, 0.f, 0.f};

#pragma unroll
    for (int kk = 0; kk < 4; ++kk) {
        const int posr = ((32 * kk + 8 * g) + 8 * n15) & 127;
#pragma unroll
        for (int j = 0; j < 16; ++j) {
            const short8 bh = *reinterpret_cast<const short8*>(&phi[(16 * j + n15) * 128 + posr]);
            acc[j] = __builtin_amdgcn_mfma_f32_16x16x32_bf16(ahi[kk], bh, acc[j], 0, 0, 0);
            acc[j] = __builtin_amdgcn_mfma_f32_16x16x32_bf16(alo[kk], bh, acc[j], 0, 0, 0);
        }
    }

    // ---- rel[256] per row: lane partial over its 32 dims of row n15,
    //      xor16+xor32 combine g-groups -> lane l holds rel256 of row l&15. ----
    float rel_part = 0.f;
#pragma unroll
    for (int kk = 0; kk < 4; ++kk) {
        const short8 ph = *reinterpret_cast<const short8*>(&phi[256 * 128 + 32 * kk + 8 * g]);
#pragma unroll
        for (int e = 0; e < 8; ++e) {
            const float qv = __uint_as_float(((uint)(ushort)ahi[kk][e]) << 16)
                           + __uint_as_float(((uint)(ushort)alo[kk][e]) << 16);
            const float pv = __uint_as_float(((uint)(ushort)ph[e]) << 16);
            rel_part = fmaf(qv, pv, rel_part);
        }
    }
    rel_part += __shfl_xor(rel_part, 16, 64);
    rel_part += __shfl_xor(rel_part, 32, 64);

    // ---- phi is dead in EVERY wave after this barrier: overlay rev. ----
    __syncthreads();

    // ---- epilogue: rows grouped by c = row&3 (4 rows per group, u slot = g).
    //      Spill reversed+shifted window (full-lane), pads, then 4 rows x
    //      4 k-groups of {splat | one aligned b128 read} + store. ----
#pragma unroll
    for (int c = 0; c < 4; ++c) {
        // main spill: win[16j+n15] of row 4g+c -> rev[w][g][256 + c - 16j - n15]
#pragma unroll
        for (int j = 0; j < 16; ++j)
            rev[w][g][256 + c - 16 * j - n15] = acc[j][c];

        // pads + win[256]: lanes of group g serve sub-buffer u=g.
        {
            const float rel_r = __shfl(rel_part, 4 * g + c, 64);   // rel256 of row 4g+c
            const float r0_r  = __shfl(acc[0][c], 16 * g, 64);     // win[0]  of row 4g+c
            if (n15 <= 3) {
                if (n15 <= c) rev[w][g][n15] = rel_r;              // p in [0, c]
            } else if (n15 <= 10) {
                const int p = 253 + n15;                           // p in [257, 263]
                if (p >= 257 + c) rev[w][g][p] = r0_r;
            }
        }
        // DS in-order per wave + may-alias: reads below observe writes above.

#pragma unroll
        for (int u = 0; u < 4; ++u) {
            const int gRow = waveRow0 + 4 * u + c;
            const int t = gRow & (T_Q - 1);                        // t === c (mod 4)
            const int ofs = 128 - t + c;
            float* orow = out + (size_t)gRow * T_Q;
            const float rr256 = RL(rel_part, 4 * u + c);
            const float rr0   = RL(acc[0][c], 16 * u);

#pragma unroll
            for (int k = 0; k < 4; ++k) {
                const int s0 = 4 * l + 256 * k;
                const int j0 = t + 128 - s0;          // jraw at first component
                float4 v;
                if (j0 <= 0) {                         // all right-clipped -> win[0]
                    v = make_float4(rr0, rr0, rr0, rr0);
                } else if (j0 >= 259) {                // all left-clipped -> win[256]
                    v = make_float4(rr256, rr256, rr256, rr256);
                } else {                               // one aligned b128: p0 = s0+ofs
                    v = *reinterpret_cast<const float4*>(&rev[w][u][s0 + ofs]);
                }
                reinterpret_cast<float4*>(orow)[l + 64 * k] = v;   // fire-and-forget
            }
        }
        // next c's spill writes cannot pass this c's gather reads (DS in-order).
    }
}

extern "C" void kernel_launch(void* const* d_in, const int* in_sizes, int n_in,
                              void* d_out, int out_size, void* d_ws, size_t ws_size,
                              hipStream_t stream)
{
    const float* Q  = (const float*)d_in[0];
    // d_in[1] is K: only its shape matters (t_k = 1024), data unused.
    const float* pe = (const float*)d_in[2];
    float* out = (float*)d_out;

    const int total_rows = in_sizes[0] / D_DIM;        // m*h*t = 65536
    const int grid = total_rows / ROWS_PER_BLOCK;      // 1024 -> 2 shifts of 2/CU
    rpe_mfma<<<grid, BLOCK_THREADS, 0, stream>>>(Q, pe, out);
}

// Round 15
// 67.604 us; speedup vs baseline: 1.5918x; 1.0364x over previous
//
#include <hip/hip_runtime.h>

// Problem constants: m=4, h=16, t=1024, d=128, MAX_REL=128.
constexpr int D_DIM = 128;
constexpr int T_Q   = 1024;
constexpr int NPE   = 257;               // 2*MAX_REL + 1 pe rows
constexpr int WAVES = 8;                 // 512-thread persistent block
constexpr int BLOCK_THREADS  = WAVES * 64;
constexpr int ROWS_PER_BLOCK = 256;      // grid 256 -> one block per CU
// Each wave owns 32 rows = 2 M-tiles of 16; 2 iterations, no sync after staging.

typedef __attribute__((ext_vector_type(8))) short short8;  // bf16x8 MFMA operand
typedef __attribute__((ext_vector_type(4))) float f32x4;   // MFMA accumulator

// readlane: uniform lane index -> SGPR broadcast, no DS/memory.
#define RL(V, SRC) __uint_as_float(__builtin_amdgcn_readlane(__float_as_uint(V), (SRC)))

// Window GEMM per wave-iteration: D[16 rows][257 pe-rows] = Q_tile . pe^T, K=128.
// Precision: pe -> bf16 RNE; q -> hi + lo (truncation split), 2 MFMA passes.
// Layout contract (k-permutation-invariant): A row m = lane&15, B col n =
// lane&15, k-dims {32kk+8g+e} in matching slots. C/D (HW-verified m89):
// col = lane&15, row = (lane>>4)*4 + reg.
//
// Pipeline rationale (r15): ONE barrier total. phi and rev coexist (no overlay)
// so waves never re-sync after staging; all Q is loaded AND converted before
// the first store, so no vmcnt wait can drain the store queue; each wave's
// iter-2 compute hides its (and other waves') iter-1 store drain. Store flow
// is continuous per CU instead of phase-locked bursts.
//
// Epilogue (as r11-r14): per row c=row&3, window stored REVERSED with shift c
// into rev[w][u][p] (pads cover clip regions); out[s0..s0+3] = one aligned
// ds_read_b128; far-clip groups splat r0/r256. DS in-order per wave keeps
// write->read safe without barriers; rev is per-wave.
__global__ __launch_bounds__(BLOCK_THREADS, 2)   // 2 waves/EU -> <=256 VGPR
void rpe_mfma(const float* __restrict__ Q,
              const float* __restrict__ pe,
              float* __restrict__ out)
{
    __shared__ ushort phi[NPE * 128];            // 65792 B, live whole kernel
    __shared__ float  rev[WAVES][4][264];        // 33792 B, per-wave private

    const int tid = threadIdx.x;
    const int w   = tid >> 6;
    const int l   = tid & 63;
    const int n15 = l & 15;
    const int g   = l >> 4;

    // ---- stage pe -> phi as bf16 (RNE), rotated +8*(n&15); one float4 read
    //      -> one ds_write_b64 of 4 bf16 (posr0 multiple of 4, never wraps). ----
    for (int q4 = tid; q4 < NPE * 32; q4 += BLOCK_THREADS) {
        const int n  = q4 >> 5;
        const int d0 = (q4 & 31) * 4;
        const float4 f = *reinterpret_cast<const float4*>(pe + n * 128 + d0);
        const float fv[4] = {f.x, f.y, f.z, f.w};
        ushort h[4];
#pragma unroll
        for (int e = 0; e < 4; ++e) {
            const uint u = __float_as_uint(fv[e]);
            h[e] = (ushort)((u + 0x7FFFu + ((u >> 16) & 1u)) >> 16);   // RNE
        }
        const int posr0 = (d0 + 8 * (n & 15)) & 127;
        *reinterpret_cast<uint2*>(&phi[n * 128 + posr0]) = *reinterpret_cast<uint2*>(h);
    }
    __syncthreads();     // the ONLY barrier in the kernel

    const int waveRow0 = blockIdx.x * ROWS_PER_BLOCK + w * 32;

    // ---- BOTH tiles' A-fragments loaded and converted up-front: after this,
    //      the wave issues no vmem loads ever again (stores cannot be drained
    //      by any later wait). Lane holds row (tileRow0 + n15), dims 32kk+8g..+7. ----
    short8 ahi[2][4], alo[2][4];
#pragma unroll
    for (int i = 0; i < 2; ++i) {
        const float* qrow = Q + (size_t)(waveRow0 + 16 * i + n15) * D_DIM;
#pragma unroll
        for (int kk = 0; kk < 4; ++kk) {
            const int base = 32 * kk + 8 * g;
            const float4 a0 = *reinterpret_cast<const float4*>(qrow + base);
            const float4 a1 = *reinterpret_cast<const float4*>(qrow + base + 4);
            const float av[8] = {a0.x, a0.y, a0.z, a0.w, a1.x, a1.y, a1.z, a1.w};
#pragma unroll
            for (int e = 0; e < 8; ++e) {
                const uint u = __float_as_uint(av[e]);
                ahi[i][kk][e] = (short)(u >> 16);            // truncation: residual exact
                const float fl = av[e] - __uint_as_float(u & 0xffff0000u);
                alo[i][kk][e] = (short)(__float_as_uint(fl) >> 16);
            }
        }
    }

    // ---- 2 independent iterations; waves free-drift, stores fire-and-forget. ----
#pragma unroll
    for (int i = 0; i < 2; ++i) {
        const int gRow0 = waveRow0 + 16 * i;

        // MFMA main: 16 n-tiles x 4 k-steps x 2 passes = 128 MFMA.
        f32x4 acc[16];
#pragma unroll
        for (int j = 0; j < 16; ++j) acc[j] = (f32x4){0.f, 0.f, 0.f, 0.f};

#pragma unroll
        for (int kk = 0; kk < 4; ++kk) {
            const int posr = ((32 * kk + 8 * g) + 8 * n15) & 127;
#pragma unroll
            for (int j = 0; j < 16; ++j) {
                const short8 bh = *reinterpret_cast<const short8*>(&phi[(16 * j + n15) * 128 + posr]);
                acc[j] = __builtin_amdgcn_mfma_f32_16x16x32_bf16(ahi[i][kk], bh, acc[j], 0, 0, 0);
                acc[j] = __builtin_amdgcn_mfma_f32_16x16x32_bf16(alo[i][kk], bh, acc[j], 0, 0, 0);
            }
        }

        // rel[256] per row: lane partial over its 32 dims of row n15,
        // xor16+xor32 combine g-groups -> lane l holds rel256 of row l&15.
        float rel_part = 0.f;
#pragma unroll
        for (int kk = 0; kk < 4; ++kk) {
            const short8 ph = *reinterpret_cast<const short8*>(&phi[256 * 128 + 32 * kk + 8 * g]);
#pragma unroll
            for (int e = 0; e < 8; ++e) {
                const float qv = __uint_as_float(((uint)(ushort)ahi[i][kk][e]) << 16)
                               + __uint_as_float(((uint)(ushort)alo[i][kk][e]) << 16);
                const float pv = __uint_as_float(((uint)(ushort)ph[e]) << 16);
                rel_part = fmaf(qv, pv, rel_part);
            }
        }
        rel_part += __shfl_xor(rel_part, 16, 64);
        rel_part += __shfl_xor(rel_part, 32, 64);

        // epilogue: rows grouped by c = row&3 (4 rows per group, u slot = g).
#pragma unroll
        for (int c = 0; c < 4; ++c) {
            // main spill: win[16j+n15] of row 4g+c -> rev[w][g][256 + c - 16j - n15]
#pragma unroll
            for (int j = 0; j < 16; ++j)
                rev[w][g][256 + c - 16 * j - n15] = acc[j][c];

            // pads + win[256]: lanes of group g serve sub-buffer u=g.
            {
                const float rel_r = __shfl(rel_part, 4 * g + c, 64);   // rel256 of row 4g+c
                const float r0_r  = __shfl(acc[0][c], 16 * g, 64);     // win[0]  of row 4g+c
                if (n15 <= 3) {
                    if (n15 <= c) rev[w][g][n15] = rel_r;              // p in [0, c]
                } else if (n15 <= 10) {
                    const int p = 253 + n15;                           // p in [257, 263]
                    if (p >= 257 + c) rev[w][g][p] = r0_r;
                }
            }
            // DS in-order per wave + may-alias: reads below observe writes above.

#pragma unroll
            for (int u = 0; u < 4; ++u) {
                const int gRow = gRow0 + 4 * u + c;
                const int t = gRow & (T_Q - 1);                        // t === c (mod 4)
                const int ofs = 128 - t + c;
                float* orow = out + (size_t)gRow * T_Q;
                const float rr256 = RL(rel_part, 4 * u + c);
                const float rr0   = RL(acc[0][c], 16 * u);

#pragma unroll
                for (int k = 0; k < 4; ++k) {
                    const int s0 = 4 * l + 256 * k;
                    const int j0 = t + 128 - s0;          // jraw at first component
                    float4 v;
                    if (j0 <= 0) {                         // all right-clipped -> win[0]
                        v = make_float4(rr0, rr0, rr0, rr0);
                    } else if (j0 >= 259) {                // all left-clipped -> win[256]
                        v = make_float4(rr256, rr256, rr256, rr256);
                    } else {                               // one aligned b128: p0 = s0+ofs
                        v = *reinterpret_cast<const float4*>(&rev[w][u][s0 + ofs]);
                    }
                    reinterpret_cast<float4*>(orow)[l + 64 * k] = v;   // fire-and-forget
                }
            }
            // next c's spill writes cannot pass this c's gather reads (DS in-order).
        }
    }
}

extern "C" void kernel_launch(void* const* d_in, const int* in_sizes, int n_in,
                              void* d_out, int out_size, void* d_ws, size_t ws_size,
                              hipStream_t stream)
{
    const float* Q  = (const float*)d_in[0];
    // d_in[1] is K: only its shape matters (t_k = 1024), data unused.
    const float* pe = (const float*)d_in[2];
    float* out = (float*)d_out;

    const int total_rows = in_sizes[0] / D_DIM;        // m*h*t = 65536
    const int grid = total_rows / ROWS_PER_BLOCK;      // 256 -> 1 persistent block/CU
    rpe_mfma<<<grid, BLOCK_THREADS, 0, stream>>>(Q, pe, out);
}